// Round 1
// baseline (259.812 us; speedup 1.0000x reference)
//
#include <hip/hip_runtime.h>
#include <math.h>

#define TBL 2048
#define E_PB 8

// workspace layout (float offsets)
#define OFF_V      0        // 64
#define OFF_S0     64       // 1
#define OFF_MM     66       // 2 uints (encoded min/max)
#define OFF_C2     128      // 128
#define OFF_EMB    256      // 128
#define OFF_M      512      // 128*64
#define OFF_WGT    8704     // 32*128 accumulator copies
#define OFF_W2T    12800    // 512*256
#define OFF_W3T    143872   // 256*128
#define OFF_SCORES 176640   // N

__device__ __forceinline__ unsigned encf(float f) {
    unsigned u = __float_as_uint(f);
    return (u & 0x80000000u) ? ~u : (u | 0x80000000u);
}
__device__ __forceinline__ float decf(unsigned u) {
    return __uint_as_float((u & 0x80000000u) ? (u & 0x7fffffffu) : ~u);
}

// ---------------- K1: fold weights, transpose W2/W3, init accumulators ----
__global__ void __launch_bounds__(256) k1_prep(
        const float* __restrict__ X,  const float* __restrict__ We,
        const float* __restrict__ be, const float* __restrict__ Wv,
        const float* __restrict__ Wq, const float* __restrict__ bq,
        const float* __restrict__ Wk, const float* __restrict__ bk,
        const float* __restrict__ W2, const float* __restrict__ W3,
        const int* __restrict__ selfp, float* ws)
{
    const int b = blockIdx.x, t = threadIdx.x;
    if (b == 0) {
        __shared__ float emb[128], q[128], u[128];
        const int self = *selfp;
        const float* xs = X + (size_t)self * 64;
        if (t < 128) {
            float acc = be[t];
            for (int d = 0; d < 64; ++d) acc = __builtin_fmaf(We[t*64 + d], xs[d], acc);
            emb[t] = acc;
            ws[OFF_EMB + t] = acc;
        }
        __syncthreads();
        if (t < 128) {
            float acc = bq[t];
            for (int f = 0; f < 128; ++f) acc = __builtin_fmaf(Wq[t*128 + f], emb[f], acc);
            q[t] = acc;
        }
        __syncthreads();
        if (t < 128) {
            float acc = 0.f;
            for (int e = 0; e < 128; ++e) acc = __builtin_fmaf(Wk[e*128 + t], q[e], acc);
            u[t] = acc;
        }
        __syncthreads();
        const float rs = 0.08838834764831845f;  // 1/sqrt(128)
        if (t < 64) {
            float acc = 0.f;
            for (int e = 0; e < 128; ++e) acc = __builtin_fmaf(We[e*64 + t], u[e], acc);
            ws[OFF_V + t] = acc * rs;
        }
        if (t == 0) {
            float acc = 0.f;
            for (int e = 0; e < 128; ++e) acc += be[e]*u[e] + bk[e]*q[e];
            ws[OFF_S0] = acc * rs;
            unsigned* mm = (unsigned*)(ws + OFF_MM);
            mm[0] = 0xFFFFFFFFu;  // encoded min init (largest)
            mm[1] = 0u;           // encoded max init (smallest)
        }
        for (int i = t; i < 32*128; i += 256) ws[OFF_WGT + i] = 0.f;
    } else if (b <= 128) {
        const int r = b - 1;  // M row r = (Wv @ We)[r], c2[r] = (Wv @ be)[r]
        if (t < 64) {
            float acc = 0.f;
            for (int e = 0; e < 128; ++e) acc = __builtin_fmaf(Wv[r*128 + e], We[e*64 + t], acc);
            ws[OFF_M + r*64 + t] = acc;
        } else if (t == 64) {
            float acc = 0.f;
            for (int e = 0; e < 128; ++e) acc = __builtin_fmaf(Wv[r*128 + e], be[e], acc);
            ws[OFF_C2 + r] = acc;
        }
    } else if (b <= 192) {
        const int base = (b - 129) * 2048;   // W2T[512][256] = W2[256][512]^T
        for (int i = t; i < 2048; i += 256) {
            const int idx = base + i;
            const int k = idx >> 8, c = idx & 255;
            ws[OFF_W2T + idx] = W2[c*512 + k];
        }
    } else {
        const int base = (b - 193) * 2048;   // W3T[256][128] = W3[128][256]^T
        for (int i = t; i < 2048; i += 256) {
            const int idx = base + i;
            const int k = idx >> 7, c = idx & 127;
            ws[OFF_W3T + idx] = W3[c*256 + k];
        }
    }
}

// ---------------- K2: scores = X@v + s0, plus global min/max --------------
__global__ void __launch_bounds__(256) k2_scores(const float4* __restrict__ X4,
                                                 float* ws, int N)
{
    const int t = threadIdx.x;
    const int lane = t & 63;
    const int wv = t >> 6;        // wave in block
    const int grp = lane >> 4;    // agent slot in wave
    const int l16 = lane & 15;    // lane within 16-lane agent group
    const float4 vch = *(const float4*)(ws + OFF_V + l16*4);
    const float s0 = ws[OFF_S0];
    float* scores = ws + OFF_SCORES;
    float smin = INFINITY, smax = -INFINITY;
    const int iters = (N + 15) >> 4;
    for (int it = blockIdx.x; it < iters; it += gridDim.x) {
        const int n = it*16 + wv*4 + grp;
        const bool ok = (n < N);
        float s = 0.f;
        if (ok) {
            const float4 xv = X4[(size_t)n*16 + l16];
            s = xv.x*vch.x + xv.y*vch.y + xv.z*vch.z + xv.w*vch.w;
        }
        s += __shfl_xor(s, 1);
        s += __shfl_xor(s, 2);
        s += __shfl_xor(s, 4);
        s += __shfl_xor(s, 8);
        s += s0;
        if (ok) {
            if (l16 == 0) scores[n] = s;
            smin = fminf(smin, s);
            smax = fmaxf(smax, s);
        }
    }
    #pragma unroll
    for (int m = 32; m >= 1; m >>= 1) {
        smin = fminf(smin, __shfl_xor(smin, m));
        smax = fmaxf(smax, __shfl_xor(smax, m));
    }
    __shared__ float rmn[4], rmx[4];
    if (lane == 0) { rmn[wv] = smin; rmx[wv] = smax; }
    __syncthreads();
    if (t == 0) {
        const float mn = fminf(fminf(rmn[0], rmn[1]), fminf(rmn[2], rmn[3]));
        const float mx = fmaxf(fmaxf(rmx[0], rmx[1]), fmaxf(rmx[2], rmx[3]));
        atomicMin((unsigned*)(ws + OFF_MM), encf(mn));
        atomicMax((unsigned*)(ws + OFF_MM) + 1, encf(mx));
    }
}

// ---------------- K3: build softmax-weight table over [smin, smax] --------
__global__ void __launch_bounds__(256) k3_table(
        const float* __restrict__ W1, const float* __restrict__ b1,
        const float* __restrict__ b2, const float* __restrict__ b3,
        float* ws, int offTab)
{
    __shared__ float h1[E_PB][512];
    __shared__ float h2[E_PB][256];
    __shared__ float sm[E_PB][128];
    const int t = threadIdx.x;
    const unsigned* mm = (const unsigned*)(ws + OFF_MM);
    const float smin = decf(mm[0]);
    const float smax = decf(mm[1]);
    const float step = (smax - smin) / (float)(TBL - 1);
    const int e0 = blockIdx.x * E_PB;

    for (int idx = t; idx < E_PB*512; idx += 256) {   // layer 1 (scalar -> 512)
        const int e = idx >> 9, k = idx & 511;
        const float s = smin + step * (float)(e0 + e);
        h1[e][k] = fmaxf(0.f, __builtin_fmaf(s, W1[k], b1[k]));
    }
    __syncthreads();
    {   // layer 2: thread t owns output column t, 8 entries
        float acc[E_PB];
        const float bb = b2[t];
        #pragma unroll
        for (int e = 0; e < E_PB; ++e) acc[e] = bb;
        const float* w2t = ws + OFF_W2T;
        for (int k = 0; k < 512; ++k) {
            const float w = w2t[k*256 + t];
            #pragma unroll
            for (int e = 0; e < E_PB; ++e) acc[e] = __builtin_fmaf(w, h1[e][k], acc[e]);
        }
        #pragma unroll
        for (int e = 0; e < E_PB; ++e) h2[e][t] = fmaxf(0.f, acc[e]);
    }
    __syncthreads();
    {   // layer 3: c = t&127, half = t>>7 covers 4 entries
        const int c = t & 127, hf = t >> 7;
        float acc[4];
        const float bb = b3[c];
        #pragma unroll
        for (int e = 0; e < 4; ++e) acc[e] = bb;
        const float* w3t = ws + OFF_W3T;
        for (int k = 0; k < 256; ++k) {
            const float w = w3t[k*128 + c];
            #pragma unroll
            for (int e = 0; e < 4; ++e) acc[e] = __builtin_fmaf(w, h2[hf*4 + e][k], acc[e]);
        }
        #pragma unroll
        for (int e = 0; e < 4; ++e) sm[hf*4 + e][c] = fmaxf(0.f, acc[e]);
    }
    __syncthreads();
    if (t < 128) {   // softmax per entry (16 lanes per entry), write pair table
        const int e = t >> 4, l = t & 15;
        float m = -INFINITY;
        #pragma unroll
        for (int i = 0; i < 8; ++i) m = fmaxf(m, sm[e][l + 16*i]);
        #pragma unroll
        for (int msk = 1; msk < 16; msk <<= 1) m = fmaxf(m, __shfl_xor(m, msk));
        float p = 0.f;
        #pragma unroll
        for (int i = 0; i < 8; ++i) p += __expf(sm[e][l + 16*i] - m);
        #pragma unroll
        for (int msk = 1; msk < 16; msk <<= 1) p += __shfl_xor(p, msk);
        const float inv = 1.f / p;
        float* tab = ws + offTab;   // float2 pairs: tab[2*(row*128+c)] = {T[row], T[row+1]}
        const int row = e0 + e;
        #pragma unroll
        for (int i = 0; i < 8; ++i) {
            const int c = l + 16*i;
            const float wgt = __expf(sm[e][c] - m) * inv;
            if (row < TBL - 1) tab[2*(row*128 + c) + 0] = wgt;
            if (row >= 1)      tab[2*((row-1)*128 + c) + 1] = wgt;
        }
    }
}

// ---------------- K4: weighted_j = sum_n w_j(s_n) * (M[j]·x_n + c2_j) -----
__global__ void __launch_bounds__(256) k4_main(const float4* __restrict__ X4,
        const int* __restrict__ selfp, float* ws, int N, int offTab)
{
    __shared__ float xs[64*64];
    const int t = threadIdx.x;
    const int j = t & 127;        // output channel
    const int slot = t >> 7;      // agent parity slot
    const int self = *selfp;
    float Mr[64];
    #pragma unroll
    for (int d = 0; d < 64; ++d) Mr[d] = ws[OFF_M + j*64 + d];
    const float c2j = ws[OFF_C2 + j];
    const unsigned* mm = (const unsigned*)(ws + OFF_MM);
    const float smin = decf(mm[0]);
    const float smax = decf(mm[1]);
    const float inv_step = (smax > smin) ? (float)(TBL - 1) / (smax - smin) : 0.f;
    const float* scores = ws + OFF_SCORES;
    const float2* tabP = (const float2*)(ws + offTab);
    float rho = 0.f;
    const int nchunks = (N + 63) >> 6;
    for (int ch = blockIdx.x; ch < nchunks; ch += gridDim.x) {
        const int base = ch << 6;
        const int valid = min(64, N - base);
        __syncthreads();
        for (int i = t; i < valid*16; i += 256)
            ((float4*)xs)[i] = X4[(size_t)base*16 + i];
        __syncthreads();
        for (int a = slot; a < valid; a += 2) {
            const int n = base + a;
            const float s = scores[n];                 // uniform -> scalar load
            const float fi = (s - smin) * inv_step;
            int ii = (int)fi;
            ii = max(0, min(TBL - 2, ii));
            const float f = fi - (float)ii;
            const float2 tp = tabP[ii*128 + j];        // coalesced 8B/lane
            const float w = tp.x + f * (tp.y - tp.x);
            const float* xa = xs + a*64;               // LDS broadcast reads
            float d0 = 0.f, d1 = 0.f, d2 = 0.f, d3 = 0.f;
            #pragma unroll
            for (int d = 0; d < 64; d += 4) {
                d0 = __builtin_fmaf(Mr[d+0], xa[d+0], d0);
                d1 = __builtin_fmaf(Mr[d+1], xa[d+1], d1);
                d2 = __builtin_fmaf(Mr[d+2], xa[d+2], d2);
                d3 = __builtin_fmaf(Mr[d+3], xa[d+3], d3);
            }
            const float val = (d0 + d1) + (d2 + d3) + c2j;
            rho += (n == self) ? 0.f : w * val;
        }
    }
    atomicAdd(&ws[OFF_WGT + ((blockIdx.x*2 + slot) & 31)*128 + j], rho);
}

// ---------------- K5: critic head ----------------------------------------
__global__ void __launch_bounds__(128) k5_final(
        const float* __restrict__ Wo1, const float* __restrict__ bo1,
        const float* __restrict__ Wo2, const float* __restrict__ bo2,
        float* ws, float* out)
{
    __shared__ float es[128], wg[128], red[128];
    const int t = threadIdx.x;
    es[t] = ws[OFF_EMB + t];
    float s = 0.f;
    for (int c = 0; c < 32; ++c) s += ws[OFF_WGT + c*128 + t];
    wg[t] = s;
    __syncthreads();
    float acc = bo1[t];
    for (int i = 0; i < 128; ++i) acc = __builtin_fmaf(Wo1[t*256 + i], es[i], acc);
    for (int i = 0; i < 128; ++i) acc = __builtin_fmaf(Wo1[t*256 + 128 + i], wg[i], acc);
    red[t] = fmaxf(acc, 0.f) * Wo2[t];
    __syncthreads();
    for (int m = 64; m >= 1; m >>= 1) {
        if (t < m) red[t] += red[t + m];
        __syncthreads();
    }
    if (t == 0) out[0] = red[0] + bo2[0];
}

extern "C" void kernel_launch(void* const* d_in, const int* in_sizes, int n_in,
                              void* d_out, int out_size, void* d_ws, size_t ws_size,
                              hipStream_t stream)
{
    const float* X   = (const float*)d_in[0];
    const float* We  = (const float*)d_in[1];
    const float* be  = (const float*)d_in[2];
    const float* Wv  = (const float*)d_in[3];
    const float* Wq  = (const float*)d_in[4];
    const float* bq  = (const float*)d_in[5];
    const float* Wk  = (const float*)d_in[6];
    const float* bk  = (const float*)d_in[7];
    const float* W1  = (const float*)d_in[8];
    const float* b1  = (const float*)d_in[9];
    const float* W2  = (const float*)d_in[10];
    const float* b2  = (const float*)d_in[11];
    const float* W3  = (const float*)d_in[12];
    const float* b3  = (const float*)d_in[13];
    const float* Wo1 = (const float*)d_in[14];
    const float* bo1 = (const float*)d_in[15];
    const float* Wo2 = (const float*)d_in[16];
    const float* bo2 = (const float*)d_in[17];
    const int* selfp = (const int*)d_in[18];
    float* ws = (float*)d_ws;
    float* out = (float*)d_out;

    const int N = in_sizes[0] / 64;
    const int offTab = OFF_SCORES + ((N + 63) & ~63);   // even -> float2-aligned
    const int nchunks = (N + 63) / 64;
    const int g4 = (nchunks + 1) / 2;

    k1_prep<<<209, 256, 0, stream>>>(X, We, be, Wv, Wq, bq, Wk, bk, W2, W3, selfp, ws);
    k2_scores<<<1024, 256, 0, stream>>>((const float4*)X, ws, N);
    k3_table<<<TBL / E_PB, 256, 0, stream>>>(W1, b1, b2, b3, ws, offTab);
    k4_main<<<g4, 256, 0, stream>>>((const float4*)X, selfp, ws, N, offTab);
    k5_final<<<1, 128, 0, stream>>>(Wo1, bo1, Wo2, bo2, ws, out);
}